// Round 11
// baseline (3221.233 us; speedup 1.0000x reference)
//
#include <hip/hip_runtime.h>
#include <math.h>

#define NN 50000
#define NE 800000
#define NGRAPH 100
#define NPG 500
#define NB_SCAN 196
#define CHAIN_ELEMS ((size_t)NN * 64)
#define CH4 ((size_t)NN * 16)          // float4 elements per plane
#define GRID_PROP (NN / 4)             // 4 nodes (waves) per 256-thr block
#define CSR_CAP 1160000                // 800k edges + <=50k*7 pad (8-multiples)
#define NBKT 32

typedef long long ll;

__device__ __forceinline__ void unpack(ll v, int& r, float& w) {
    r = (int)(v & 0xffffffffLL);
    w = __int_as_float((int)(v >> 32));
}

__device__ __forceinline__ float4 f4fma(float w, float4 v, float4 a) {
    a.x += w * v.x; a.y += w * v.y; a.z += w * v.z; a.w += w * v.w;
    return a;
}

// ---------------- setup kernels ----------------

__global__ void k_deg(const int* __restrict__ col, int* __restrict__ degi) {
    int e = blockIdx.x * blockDim.x + threadIdx.x;
    if (e < NE) atomicAdd(&degi[col[e]], 1);
}

// dh + padded count (multiple of 8)
__global__ void k_dh(const int* __restrict__ degi, float* __restrict__ dh,
                     int* __restrict__ cntp) {
    int i = blockIdx.x * blockDim.x + threadIdx.x;
    if (i < NN) {
        int d = degi[i];
        dh[i] = d > 0 ? (float)(1.0 / sqrt((double)d)) : 0.0f;
        cntp[i] = (d + 7) & ~7;
    }
}

__global__ void k_bsum(const int* __restrict__ cnt, int* __restrict__ bsum) {
    __shared__ int sh[256];
    int i = blockIdx.x * 256 + threadIdx.x;
    sh[threadIdx.x] = (i < NN) ? cnt[i] : 0;
    __syncthreads();
    for (int s = 128; s > 0; s >>= 1) {
        if (threadIdx.x < s) sh[threadIdx.x] += sh[threadIdx.x + s];
        __syncthreads();
    }
    if (threadIdx.x == 0) bsum[blockIdx.x] = sh[0];
}

__global__ void k_bscan(const int* __restrict__ bsum, int* __restrict__ boff) {
    __shared__ int sh[2][256];
    int v = (threadIdx.x < NB_SCAN) ? bsum[threadIdx.x] : 0;
    int cur = 0;
    sh[0][threadIdx.x] = v;
    __syncthreads();
    for (int s = 1; s < 256; s <<= 1) {
        int val = sh[cur][threadIdx.x];
        if ((int)threadIdx.x >= s) val += sh[cur][threadIdx.x - s];
        sh[cur ^ 1][threadIdx.x] = val;
        cur ^= 1;
        __syncthreads();
    }
    if (threadIdx.x < NB_SCAN) boff[threadIdx.x] = sh[cur][threadIdx.x] - v;
}

__global__ void k_scan2(const int* __restrict__ cnt, const int* __restrict__ boff,
                        int* __restrict__ off) {
    __shared__ int sh[2][256];
    int i = blockIdx.x * 256 + threadIdx.x;
    int v = (i < NN) ? cnt[i] : 0;
    int cur = 0;
    sh[0][threadIdx.x] = v;
    __syncthreads();
    for (int s = 1; s < 256; s <<= 1) {
        int val = sh[cur][threadIdx.x];
        if ((int)threadIdx.x >= s) val += sh[cur][threadIdx.x - s];
        sh[cur ^ 1][threadIdx.x] = val;
        cur ^= 1;
        __syncthreads();
    }
    if (i < NN) off[i] = boff[blockIdx.x] + sh[cur][threadIdx.x] - v;
}

__global__ void k_fill(const int* __restrict__ row, const int* __restrict__ col,
                       const float* __restrict__ dh, const int* __restrict__ offp,
                       int* __restrict__ cursor, ll* __restrict__ csrp) {
    int e = blockIdx.x * blockDim.x + threadIdx.x;
    if (e >= NE) return;
    int r = row[e], c = col[e];
    int pos = offp[c] + atomicAdd(&cursor[c], 1);
    float w = dh[r] * dh[c];
    csrp[pos] = ((ll)__float_as_int(w) << 32) | (unsigned int)r;
}

// ---- counting sort of nodes by trip count (descending) for load balance ----

__global__ void k_hist(const int* __restrict__ cntp, int* __restrict__ hist) {
    int i = blockIdx.x * blockDim.x + threadIdx.x;
    if (i < NN) {
        int b = cntp[i] >> 3; if (b > NBKT - 1) b = NBKT - 1;
        atomicAdd(&hist[NBKT - 1 - b], 1);   // descending key
    }
}

__global__ void k_hoff(const int* __restrict__ hist, int* __restrict__ hoff) {
    if (threadIdx.x == 0) {
        int acc = 0;
        for (int b = 0; b < NBKT; ++b) { hoff[b] = acc; acc += hist[b]; }
    }
}

__global__ void k_perm(const int* __restrict__ cntp, const int* __restrict__ hoff,
                       int* __restrict__ hcur, int* __restrict__ perm) {
    int i = blockIdx.x * blockDim.x + threadIdx.x;
    if (i < NN) {
        int b = cntp[i] >> 3; if (b > NBKT - 1) b = NBKT - 1;
        int k = NBKT - 1 - b;
        perm[hoff[k] + atomicAdd(&hcur[k], 1)] = i;
    }
}

// ---------------- recurrence kernel (fp32, [NN][64], float4 gathers) --------
// wave = 1 node (perm-ordered). lane = eg*16 + cq. CSR padded to 8-multiples
// with (r=0,w=0) so the loop is tail-free and trip count = cnt/8.

template <bool INIT>
__global__ __launch_bounds__(256) void k_prop(
    const float* __restrict__ Tcur, const float* __restrict__ Tprev,
    float* __restrict__ Tnext, const int* __restrict__ offp,
    const int* __restrict__ cntp, const ll* __restrict__ csrp,
    const int* __restrict__ perm) {
    int node = perm[blockIdx.x * 4 + (threadIdx.x >> 6)];
    int lane = threadIdx.x & 63;
    int eg = lane >> 4;
    int cq = lane & 15;
    int s = offp[node], e = s + cntp[node];
    const float* tb = Tcur + (size_t)cq * 4;
    float4 a0 = make_float4(0.f, 0.f, 0.f, 0.f);
    float4 a1 = make_float4(0.f, 0.f, 0.f, 0.f);
    float4 pv = INIT ? make_float4(0.f, 0.f, 0.f, 0.f)
                     : *(const float4*)&Tprev[(size_t)node * 64 + cq * 4];
    for (int i = s; i < e; i += 8) {
        int r0, r1; float w0, w1;
        unpack(csrp[i + eg], r0, w0);
        unpack(csrp[i + 4 + eg], r1, w1);
        a0 = f4fma(w0, *(const float4*)(tb + (size_t)r0 * 64), a0);
        a1 = f4fma(w1, *(const float4*)(tb + (size_t)r1 * 64), a1);
    }
    float4 g = make_float4(a0.x + a1.x, a0.y + a1.y, a0.z + a1.z, a0.w + a1.w);
    g.x += __shfl_xor(g.x, 16); g.y += __shfl_xor(g.y, 16);
    g.z += __shfl_xor(g.z, 16); g.w += __shfl_xor(g.w, 16);
    g.x += __shfl_xor(g.x, 32); g.y += __shfl_xor(g.y, 32);
    g.z += __shfl_xor(g.z, 32); g.w += __shfl_xor(g.w, 32);
    float4 t;
    if (INIT) {
        t = make_float4(-g.x, -g.y, -g.z, -g.w);
    } else {
        t = make_float4(-2.f * g.x - pv.x, -2.f * g.y - pv.y,
                        -2.f * g.z - pv.z, -2.f * g.w - pv.w);
    }
    if (eg == 0) *(float4*)&Tnext[(size_t)node * 64 + cq * 4] = t;
}

// ---------------- combine: acc planes from NS pool slots (float4) -----------

struct CombCfg {
    float c0[4];
    float ck[4][8];
    int   plane[4];
};

template <int NS, int NT>
__global__ __launch_bounds__(256) void k_combine(
    const float4* __restrict__ src0, const float4* __restrict__ pool,
    float4* __restrict__ accb, CombCfg cfg, int first, int doabs) {
    size_t v = (size_t)blockIdx.x * 256 + threadIdx.x;   // < NN*16
    float4 tv[NS];
#pragma unroll
    for (int m = 0; m < NS; ++m) tv[m] = pool[(size_t)m * CH4 + v];
    float4 s0 = first ? src0[v] : make_float4(0.f, 0.f, 0.f, 0.f);
#pragma unroll
    for (int t = 0; t < NT; ++t) {
        size_t o = (size_t)cfg.plane[t] * CH4 + v;
        float4 a;
        if (first) {
            float c = cfg.c0[t];
            a = make_float4(c * s0.x, c * s0.y, c * s0.z, c * s0.w);
        } else {
            a = accb[o];
        }
#pragma unroll
        for (int m = 0; m < NS; ++m) a = f4fma(cfg.ck[t][m], tv[m], a);
        if (doabs) a = make_float4(fabsf(a.x), fabsf(a.y), fabsf(a.z), fabsf(a.w));
        accb[o] = a;
    }
}

// ---------------- moments ----------------
__global__ void k_moments(const float* __restrict__ x, const float* __restrict__ hacc,
                          const float* __restrict__ acc2, float* __restrict__ out) {
    int g = blockIdx.y;
    int col = blockIdx.x * 256 + threadIdx.x;
    if (col >= 704) return;
    const float* src;
    int c0;
    if (col < 64)       { src = x;    c0 = col; }
    else if (col < 320) { int p = (col - 64) >> 6;  src = hacc + (size_t)p * CHAIN_ELEMS; c0 = (col - 64) & 63; }
    else                { int p = (col - 320) >> 6; src = acc2 + (size_t)p * CHAIN_ELEMS; c0 = (col - 320) & 63; }
    double s1 = 0, s2 = 0, s3 = 0, s4 = 0;
    int base = g * NPG;
    for (int i = 0; i < NPG; ++i) {
        double v = (double)src[(size_t)(base + i) * 64 + c0];
        double v2 = v * v;
        s1 += v; s2 += v2; s3 += v2 * v; s4 += v2 * v2;
    }
    double n = (double)NPG;
    double mu = s1 / n;
    double E2 = s2 / n, E3 = s3 / n, E4 = s4 / n;
    double m2 = E2 - mu * mu;
    double m3 = E3 - 3.0 * mu * E2 + 2.0 * mu * mu * mu;
    double m4 = E4 - 4.0 * mu * E3 + 6.0 * mu * mu * E2 - 3.0 * mu * mu * mu * mu;
    float m2f = (float)m2;
    float skew = 0.f, kurt = -3.f;
    if (m2f > 0.f) {
        skew = (float)(m3 / (m2 * sqrt(m2)));
        if (skew > 1e15f) skew = 0.f;
        kurt = (float)(m4 / (m2 * m2) - 3.0);
        if (kurt > 1e15f) kurt = -3.f;
    }
    size_t ob = (size_t)g * 2816 + col;
    out[ob]        = (float)mu;
    out[ob + 704]  = m2f;
    out[ob + 1408] = skew;
    out[ob + 2112] = kurt;
}

// ---------------- host ----------------

extern "C" void kernel_launch(void* const* d_in, const int* in_sizes, int n_in,
                              void* d_out, int out_size, void* d_ws, size_t ws_size,
                              hipStream_t stream) {
    const float* x = (const float*)d_in[0];
    const int* ei  = (const int*)d_in[1];
    const int* row = ei;
    const int* col = ei + NE;
    float* out = (float*)d_out;

    // Chebyshev coefficients [17][4], double precision (matches numpy)
    float C[17][4];
    {
        const int Nc = 17;
        const int scales[4] = {2, 4, 8, 16};
        for (int si = 0; si < 4; ++si) {
            double ker[17];
            for (int j = 0; j < Nc; ++j) {
                double num = cos(M_PI * (j + 0.5) / Nc);
                double b = -num;
                double v = pow(b, (double)(scales[si] / 2)) - pow(b, (double)scales[si]);
                if (v < 0) v = 0;
                ker[j] = sqrt(v);
            }
            for (int o = 0; o < Nc; ++o) {
                double acc = 0;
                for (int j = 0; j < Nc; ++j) acc += ker[j] * cos(M_PI * o * (j + 0.5) / Nc);
                C[o][si] = (float)(2.0 / Nc * acc);
            }
        }
    }

    // workspace carve: 8-slot pool (~241 MB); fallback 4 (~190)
    int*   degi; float* dh; int* offp; int* cntp; int* cursor; int* bsum; int* boff;
    int*   hist; int* hoff; int* hcur; int* perm;
    ll*    csrp; float* pool; float* hacc; float* acc2;
    int SLOTS = 8;
    for (int attempt = 0; attempt < 2; ++attempt) {
        char* p = (char*)d_ws;
        auto alloc = [&](size_t bytes) -> void* {
            void* r = (void*)p;
            p += (bytes + 255) & ~(size_t)255;
            return r;
        };
        degi   = (int*)alloc((size_t)NN * 4);
        dh     = (float*)alloc((size_t)NN * 4);
        offp   = (int*)alloc((size_t)NN * 4);
        cntp   = (int*)alloc((size_t)NN * 4);
        cursor = (int*)alloc((size_t)NN * 4);
        bsum   = (int*)alloc((size_t)NB_SCAN * 4);
        boff   = (int*)alloc((size_t)NB_SCAN * 4);
        hist   = (int*)alloc((size_t)NBKT * 4);
        hoff   = (int*)alloc((size_t)NBKT * 4);
        hcur   = (int*)alloc((size_t)NBKT * 4);
        perm   = (int*)alloc((size_t)NN * 4);
        csrp   = (ll*)alloc((size_t)CSR_CAP * 8);
        pool   = (float*)alloc((size_t)SLOTS * CHAIN_ELEMS * 4);
        hacc   = (float*)alloc((size_t)4 * CHAIN_ELEMS * 4);
        acc2   = (float*)alloc((size_t)6 * CHAIN_ELEMS * 4);
        if ((size_t)(p - (char*)d_ws) <= ws_size) break;
        SLOTS = 4;
    }
    const int CAD = SLOTS;   // combine cadence

    hipMemsetAsync(degi, 0, (size_t)NN * 4, stream);
    hipMemsetAsync(cursor, 0, (size_t)NN * 4, stream);
    hipMemsetAsync(hist, 0, (size_t)NBKT * 4, stream);
    hipMemsetAsync(hcur, 0, (size_t)NBKT * 4, stream);
    hipMemsetAsync(csrp, 0, (size_t)CSR_CAP * 8, stream);   // pads: r=0,w=0

    k_deg  <<<(NE + 255) / 256, 256, 0, stream>>>(col, degi);
    k_dh   <<<(NN + 255) / 256, 256, 0, stream>>>(degi, dh, cntp);
    k_bsum <<<NB_SCAN, 256, 0, stream>>>(cntp, bsum);
    k_bscan<<<1, 256, 0, stream>>>(bsum, boff);
    k_scan2<<<NB_SCAN, 256, 0, stream>>>(cntp, boff, offp);
    k_fill <<<(NE + 255) / 256, 256, 0, stream>>>(row, col, dh, offp, cursor, csrp);
    k_hist <<<NB_SCAN, 256, 0, stream>>>(cntp, hist);
    k_hoff <<<1, 64, 0, stream>>>(hist, hoff);
    k_perm <<<NB_SCAN, 256, 0, stream>>>(cntp, hoff, hcur, perm);

    auto slot = [&](int k) { return pool + (size_t)((k - 1) & (SLOTS - 1)) * CHAIN_ELEMS; };
    const int GRID_C = (int)(CH4 / 256);   // 3125

    auto launch_combine = [&](int nt, const float* src, float* accb,
                              CombCfg& cfg, int first, int doabs) {
        const float4* s4 = (const float4*)src;
        const float4* p4 = (const float4*)pool;
        float4* a4 = (float4*)accb;
        if (CAD == 8) {
            if (nt == 4) k_combine<8, 4><<<GRID_C, 256, 0, stream>>>(s4, p4, a4, cfg, first, doabs);
            if (nt == 3) k_combine<8, 3><<<GRID_C, 256, 0, stream>>>(s4, p4, a4, cfg, first, doabs);
            if (nt == 2) k_combine<8, 2><<<GRID_C, 256, 0, stream>>>(s4, p4, a4, cfg, first, doabs);
            if (nt == 1) k_combine<8, 1><<<GRID_C, 256, 0, stream>>>(s4, p4, a4, cfg, first, doabs);
        } else {
            if (nt == 4) k_combine<4, 4><<<GRID_C, 256, 0, stream>>>(s4, p4, a4, cfg, first, doabs);
            if (nt == 3) k_combine<4, 3><<<GRID_C, 256, 0, stream>>>(s4, p4, a4, cfg, first, doabs);
            if (nt == 2) k_combine<4, 2><<<GRID_C, 256, 0, stream>>>(s4, p4, a4, cfg, first, doabs);
            if (nt == 1) k_combine<4, 1><<<GRID_C, 256, 0, stream>>>(s4, p4, a4, cfg, first, doabs);
        }
    };

    // run one chain: src [NN,64] -> acc planes of accb
    auto run_chain = [&](const float* src, float* accb,
                         const int* scl, const int* pln, int nt) {
        k_prop<true><<<GRID_PROP, 256, 0, stream>>>(src, nullptr, slot(1),
                                                    offp, cntp, csrp, perm);
        for (int k = 2; k <= 16; ++k) {
            const float* Tprev = (k == 2) ? src : slot(k - 2);
            k_prop<false><<<GRID_PROP, 256, 0, stream>>>(slot(k - 1), Tprev, slot(k),
                                                         offp, cntp, csrp, perm);
            if ((k % CAD) == 0) {
                CombCfg cfg;
                for (int t = 0; t < nt; ++t) {
                    int si = scl[t];
                    cfg.c0[t] = 0.5f * C[0][si];
                    cfg.plane[t] = pln[t];
                    for (int m = 0; m < CAD; ++m) cfg.ck[t][m] = C[k - CAD + 1 + m][si];
                }
                launch_combine(nt, src, accb, cfg, (k == CAD) ? 1 : 0,
                               (k == 16) ? 1 : 0);
            }
        }
    };

    // ---- phase 1: x -> hacc planes 0..3 (|h| per scale) ----
    {
        const int scl[4] = {0, 1, 2, 3};
        const int pln[4] = {0, 1, 2, 3};
        run_chain(x, hacc, scl, pln, 4);
    }

    // ---- phase 2: 3 chains on hacc planes 0..2 ----
    {
        const int scl0[3] = {1, 2, 3}; const int pln0[3] = {0, 1, 3};
        run_chain(hacc + 0 * CHAIN_ELEMS, acc2, scl0, pln0, 3);
        const int scl1[2] = {2, 3};    const int pln1[2] = {2, 4};
        run_chain(hacc + 1 * CHAIN_ELEMS, acc2, scl1, pln1, 2);
        const int scl2[1] = {3};       const int pln2[1] = {5};
        run_chain(hacc + 2 * CHAIN_ELEMS, acc2, scl2, pln2, 1);
    }

    // ---- moments ----
    dim3 mg(3, NGRAPH);
    k_moments<<<mg, 256, 0, stream>>>(x, hacc, acc2, out);
}

// Round 12
// 2454.530 us; speedup vs baseline: 1.3124x; 1.3124x over previous
//
#include <hip/hip_runtime.h>
#include <math.h>

#define NN 50000
#define NE 800000
#define NGRAPH 100
#define NPG 500
#define NB_SCAN 196
#define CHAIN_ELEMS ((size_t)NN * 64)
#define CH4 ((size_t)NN * 16)          // float4 elements per plane
#define GRID_PROP (NN / 4)             // 4 nodes (waves) per 256-thr block
#define CSR_CAP 1160000                // 800k edges + <=50k*7 pad (8-multiples)
#define NBKT 32
#define NSCN (NBKT * NB_SCAN)          // 6272

typedef long long ll;

__device__ __forceinline__ void unpack(ll v, int& r, float& w) {
    r = (int)(v & 0xffffffffLL);
    w = __int_as_float((int)(v >> 32));
}

__device__ __forceinline__ float4 f4fma(float w, float4 v, float4 a) {
    a.x += w * v.x; a.y += w * v.y; a.z += w * v.z; a.w += w * v.w;
    return a;
}

// ---------------- setup kernels ----------------

__global__ void k_deg(const int* __restrict__ col, int* __restrict__ degi) {
    int e = blockIdx.x * blockDim.x + threadIdx.x;
    if (e < NE) atomicAdd(&degi[col[e]], 1);
}

// dh + padded count (multiple of 8)
__global__ void k_dh(const int* __restrict__ degi, float* __restrict__ dh,
                     int* __restrict__ cntp) {
    int i = blockIdx.x * blockDim.x + threadIdx.x;
    if (i < NN) {
        int d = degi[i];
        dh[i] = d > 0 ? (float)(1.0 / sqrt((double)d)) : 0.0f;
        cntp[i] = (d + 7) & ~7;
    }
}

__global__ void k_bsum(const int* __restrict__ cnt, int* __restrict__ bsum) {
    __shared__ int sh[256];
    int i = blockIdx.x * 256 + threadIdx.x;
    sh[threadIdx.x] = (i < NN) ? cnt[i] : 0;
    __syncthreads();
    for (int s = 128; s > 0; s >>= 1) {
        if (threadIdx.x < s) sh[threadIdx.x] += sh[threadIdx.x + s];
        __syncthreads();
    }
    if (threadIdx.x == 0) bsum[blockIdx.x] = sh[0];
}

__global__ void k_bscan(const int* __restrict__ bsum, int* __restrict__ boff) {
    __shared__ int sh[2][256];
    int v = (threadIdx.x < NB_SCAN) ? bsum[threadIdx.x] : 0;
    int cur = 0;
    sh[0][threadIdx.x] = v;
    __syncthreads();
    for (int s = 1; s < 256; s <<= 1) {
        int val = sh[cur][threadIdx.x];
        if ((int)threadIdx.x >= s) val += sh[cur][threadIdx.x - s];
        sh[cur ^ 1][threadIdx.x] = val;
        cur ^= 1;
        __syncthreads();
    }
    if (threadIdx.x < NB_SCAN) boff[threadIdx.x] = sh[cur][threadIdx.x] - v;
}

__global__ void k_scan2(const int* __restrict__ cnt, const int* __restrict__ boff,
                        int* __restrict__ off) {
    __shared__ int sh[2][256];
    int i = blockIdx.x * 256 + threadIdx.x;
    int v = (i < NN) ? cnt[i] : 0;
    int cur = 0;
    sh[0][threadIdx.x] = v;
    __syncthreads();
    for (int s = 1; s < 256; s <<= 1) {
        int val = sh[cur][threadIdx.x];
        if ((int)threadIdx.x >= s) val += sh[cur][threadIdx.x - s];
        sh[cur ^ 1][threadIdx.x] = val;
        cur ^= 1;
        __syncthreads();
    }
    if (i < NN) off[i] = boff[blockIdx.x] + sh[cur][threadIdx.x] - v;
}

__global__ void k_fill(const int* __restrict__ row, const int* __restrict__ col,
                       const float* __restrict__ dh, const int* __restrict__ offp,
                       int* __restrict__ cursor, ll* __restrict__ csrp) {
    int e = blockIdx.x * blockDim.x + threadIdx.x;
    if (e >= NE) return;
    int r = row[e], c = col[e];
    int pos = offp[c] + atomicAdd(&cursor[c], 1);
    float w = dh[r] * dh[c];
    csrp[pos] = ((ll)__float_as_int(w) << 32) | (unsigned int)r;
}

// ---- contention-free counting sort by trip count (descending) --------------

__global__ void k_bhist(const int* __restrict__ cntp, int* __restrict__ bh) {
    __shared__ int h[NBKT];
    if (threadIdx.x < NBKT) h[threadIdx.x] = 0;
    __syncthreads();
    int i = blockIdx.x * 256 + threadIdx.x;
    if (i < NN) {
        int b = cntp[i] >> 3; if (b > NBKT - 1) b = NBKT - 1;
        atomicAdd(&h[NBKT - 1 - b], 1);   // descending key
    }
    __syncthreads();
    if (threadIdx.x < NBKT) bh[blockIdx.x * NBKT + threadIdx.x] = h[threadIdx.x];
}

// exclusive scan over key-major counts: j = k*NB_SCAN + b  ->  goff[j]
__global__ void k_gscan(const int* __restrict__ bh, int* __restrict__ goff) {
    __shared__ int buf[2][1024];
    __shared__ int carry;
    if (threadIdx.x == 0) carry = 0;
    __syncthreads();
    for (int base = 0; base < NSCN; base += 1024) {
        int j = base + threadIdx.x;
        int v = 0;
        if (j < NSCN) {
            int k = j / NB_SCAN, b = j % NB_SCAN;
            v = bh[b * NBKT + k];
        }
        int cur = 0;
        buf[0][threadIdx.x] = v;
        __syncthreads();
        for (int s = 1; s < 1024; s <<= 1) {
            int val = buf[cur][threadIdx.x];
            if ((int)threadIdx.x >= s) val += buf[cur][threadIdx.x - s];
            buf[cur ^ 1][threadIdx.x] = val;
            cur ^= 1;
            __syncthreads();
        }
        if (j < NSCN) goff[j] = carry + buf[cur][threadIdx.x] - v;
        __syncthreads();
        if (threadIdx.x == 0) carry += buf[cur][1023];
        __syncthreads();
    }
}

__global__ void k_place(const int* __restrict__ cntp, const int* __restrict__ goff,
                        int* __restrict__ perm) {
    __shared__ int lh[NBKT];
    __shared__ int lbase[NBKT];
    if (threadIdx.x < NBKT) lh[threadIdx.x] = 0;
    __syncthreads();
    int i = blockIdx.x * 256 + threadIdx.x;
    int k = 0, rank = 0;
    bool act = i < NN;
    if (act) {
        int b = cntp[i] >> 3; if (b > NBKT - 1) b = NBKT - 1;
        k = NBKT - 1 - b;
        rank = atomicAdd(&lh[k], 1);
    }
    __syncthreads();
    if (threadIdx.x < NBKT)
        lbase[threadIdx.x] = goff[threadIdx.x * NB_SCAN + blockIdx.x];
    __syncthreads();
    if (act) perm[lbase[k] + rank] = i;
}

// ---------------- recurrence kernel (fp32, [NN][64], float4 gathers) --------
// wave = 1 node (perm-ordered). lane = eg*16 + cq. CSR padded to 8-multiples
// with (r=0,w=0) so the loop is tail-free and trip count = cnt/8.

template <bool INIT>
__global__ __launch_bounds__(256) void k_prop(
    const float* __restrict__ Tcur, const float* __restrict__ Tprev,
    float* __restrict__ Tnext, const int* __restrict__ offp,
    const int* __restrict__ cntp, const ll* __restrict__ csrp,
    const int* __restrict__ perm) {
    int node = perm[blockIdx.x * 4 + (threadIdx.x >> 6)];
    int lane = threadIdx.x & 63;
    int eg = lane >> 4;
    int cq = lane & 15;
    int s = offp[node], e = s + cntp[node];
    const float* tb = Tcur + (size_t)cq * 4;
    float4 a0 = make_float4(0.f, 0.f, 0.f, 0.f);
    float4 a1 = make_float4(0.f, 0.f, 0.f, 0.f);
    float4 pv = INIT ? make_float4(0.f, 0.f, 0.f, 0.f)
                     : *(const float4*)&Tprev[(size_t)node * 64 + cq * 4];
    for (int i = s; i < e; i += 8) {
        int r0, r1; float w0, w1;
        unpack(csrp[i + eg], r0, w0);
        unpack(csrp[i + 4 + eg], r1, w1);
        a0 = f4fma(w0, *(const float4*)(tb + (size_t)r0 * 64), a0);
        a1 = f4fma(w1, *(const float4*)(tb + (size_t)r1 * 64), a1);
    }
    float4 g = make_float4(a0.x + a1.x, a0.y + a1.y, a0.z + a1.z, a0.w + a1.w);
    g.x += __shfl_xor(g.x, 16); g.y += __shfl_xor(g.y, 16);
    g.z += __shfl_xor(g.z, 16); g.w += __shfl_xor(g.w, 16);
    g.x += __shfl_xor(g.x, 32); g.y += __shfl_xor(g.y, 32);
    g.z += __shfl_xor(g.z, 32); g.w += __shfl_xor(g.w, 32);
    float4 t;
    if (INIT) {
        t = make_float4(-g.x, -g.y, -g.z, -g.w);
    } else {
        t = make_float4(-2.f * g.x - pv.x, -2.f * g.y - pv.y,
                        -2.f * g.z - pv.z, -2.f * g.w - pv.w);
    }
    if (eg == 0) *(float4*)&Tnext[(size_t)node * 64 + cq * 4] = t;
}

// ---------------- combine: acc planes from NS pool slots (float4) -----------

struct CombCfg {
    float c0[4];
    float ck[4][8];
    int   plane[4];
};

template <int NS, int NT>
__global__ __launch_bounds__(256) void k_combine(
    const float4* __restrict__ src0, const float4* __restrict__ pool,
    float4* __restrict__ accb, CombCfg cfg, int first, int doabs) {
    size_t v = (size_t)blockIdx.x * 256 + threadIdx.x;   // < NN*16
    float4 tv[NS];
#pragma unroll
    for (int m = 0; m < NS; ++m) tv[m] = pool[(size_t)m * CH4 + v];
    float4 s0 = first ? src0[v] : make_float4(0.f, 0.f, 0.f, 0.f);
#pragma unroll
    for (int t = 0; t < NT; ++t) {
        size_t o = (size_t)cfg.plane[t] * CH4 + v;
        float4 a;
        if (first) {
            float c = cfg.c0[t];
            a = make_float4(c * s0.x, c * s0.y, c * s0.z, c * s0.w);
        } else {
            a = accb[o];
        }
#pragma unroll
        for (int m = 0; m < NS; ++m) a = f4fma(cfg.ck[t][m], tv[m], a);
        if (doabs) a = make_float4(fabsf(a.x), fabsf(a.y), fabsf(a.z), fabsf(a.w));
        accb[o] = a;
    }
}

// ---------------- moments ----------------
__global__ void k_moments(const float* __restrict__ x, const float* __restrict__ hacc,
                          const float* __restrict__ acc2, float* __restrict__ out) {
    int g = blockIdx.y;
    int col = blockIdx.x * 256 + threadIdx.x;
    if (col >= 704) return;
    const float* src;
    int c0;
    if (col < 64)       { src = x;    c0 = col; }
    else if (col < 320) { int p = (col - 64) >> 6;  src = hacc + (size_t)p * CHAIN_ELEMS; c0 = (col - 64) & 63; }
    else                { int p = (col - 320) >> 6; src = acc2 + (size_t)p * CHAIN_ELEMS; c0 = (col - 320) & 63; }
    double s1 = 0, s2 = 0, s3 = 0, s4 = 0;
    int base = g * NPG;
    for (int i = 0; i < NPG; ++i) {
        double v = (double)src[(size_t)(base + i) * 64 + c0];
        double v2 = v * v;
        s1 += v; s2 += v2; s3 += v2 * v; s4 += v2 * v2;
    }
    double n = (double)NPG;
    double mu = s1 / n;
    double E2 = s2 / n, E3 = s3 / n, E4 = s4 / n;
    double m2 = E2 - mu * mu;
    double m3 = E3 - 3.0 * mu * E2 + 2.0 * mu * mu * mu;
    double m4 = E4 - 4.0 * mu * E3 + 6.0 * mu * mu * E2 - 3.0 * mu * mu * mu * mu;
    float m2f = (float)m2;
    float skew = 0.f, kurt = -3.f;
    if (m2f > 0.f) {
        skew = (float)(m3 / (m2 * sqrt(m2)));
        if (skew > 1e15f) skew = 0.f;
        kurt = (float)(m4 / (m2 * m2) - 3.0);
        if (kurt > 1e15f) kurt = -3.f;
    }
    size_t ob = (size_t)g * 2816 + col;
    out[ob]        = (float)mu;
    out[ob + 704]  = m2f;
    out[ob + 1408] = skew;
    out[ob + 2112] = kurt;
}

// ---------------- host ----------------

extern "C" void kernel_launch(void* const* d_in, const int* in_sizes, int n_in,
                              void* d_out, int out_size, void* d_ws, size_t ws_size,
                              hipStream_t stream) {
    const float* x = (const float*)d_in[0];
    const int* ei  = (const int*)d_in[1];
    const int* row = ei;
    const int* col = ei + NE;
    float* out = (float*)d_out;

    // Chebyshev coefficients [17][4], double precision (matches numpy)
    float C[17][4];
    {
        const int Nc = 17;
        const int scales[4] = {2, 4, 8, 16};
        for (int si = 0; si < 4; ++si) {
            double ker[17];
            for (int j = 0; j < Nc; ++j) {
                double num = cos(M_PI * (j + 0.5) / Nc);
                double b = -num;
                double v = pow(b, (double)(scales[si] / 2)) - pow(b, (double)scales[si]);
                if (v < 0) v = 0;
                ker[j] = sqrt(v);
            }
            for (int o = 0; o < Nc; ++o) {
                double acc = 0;
                for (int j = 0; j < Nc; ++j) acc += ker[j] * cos(M_PI * o * (j + 0.5) / Nc);
                C[o][si] = (float)(2.0 / Nc * acc);
            }
        }
    }

    // workspace carve: 8-slot pool (~241 MB); fallback 4 (~190)
    int*   degi; float* dh; int* offp; int* cntp; int* cursor; int* bsum; int* boff;
    int*   bh; int* goff; int* perm;
    ll*    csrp; float* pool; float* hacc; float* acc2;
    int SLOTS = 8;
    for (int attempt = 0; attempt < 2; ++attempt) {
        char* p = (char*)d_ws;
        auto alloc = [&](size_t bytes) -> void* {
            void* r = (void*)p;
            p += (bytes + 255) & ~(size_t)255;
            return r;
        };
        degi   = (int*)alloc((size_t)NN * 4);
        dh     = (float*)alloc((size_t)NN * 4);
        offp   = (int*)alloc((size_t)NN * 4);
        cntp   = (int*)alloc((size_t)NN * 4);
        cursor = (int*)alloc((size_t)NN * 4);
        bsum   = (int*)alloc((size_t)NB_SCAN * 4);
        boff   = (int*)alloc((size_t)NB_SCAN * 4);
        bh     = (int*)alloc((size_t)NSCN * 4);
        goff   = (int*)alloc((size_t)NSCN * 4);
        perm   = (int*)alloc((size_t)NN * 4);
        csrp   = (ll*)alloc((size_t)CSR_CAP * 8);
        pool   = (float*)alloc((size_t)SLOTS * CHAIN_ELEMS * 4);
        hacc   = (float*)alloc((size_t)4 * CHAIN_ELEMS * 4);
        acc2   = (float*)alloc((size_t)6 * CHAIN_ELEMS * 4);
        if ((size_t)(p - (char*)d_ws) <= ws_size) break;
        SLOTS = 4;
    }
    const int CAD = SLOTS;   // combine cadence

    hipMemsetAsync(degi, 0, (size_t)NN * 4, stream);
    hipMemsetAsync(cursor, 0, (size_t)NN * 4, stream);
    hipMemsetAsync(csrp, 0, (size_t)CSR_CAP * 8, stream);   // pads: r=0,w=0

    k_deg  <<<(NE + 255) / 256, 256, 0, stream>>>(col, degi);
    k_dh   <<<(NN + 255) / 256, 256, 0, stream>>>(degi, dh, cntp);
    k_bsum <<<NB_SCAN, 256, 0, stream>>>(cntp, bsum);
    k_bscan<<<1, 256, 0, stream>>>(bsum, boff);
    k_scan2<<<NB_SCAN, 256, 0, stream>>>(cntp, boff, offp);
    k_fill <<<(NE + 255) / 256, 256, 0, stream>>>(row, col, dh, offp, cursor, csrp);
    k_bhist<<<NB_SCAN, 256, 0, stream>>>(cntp, bh);
    k_gscan<<<1, 1024, 0, stream>>>(bh, goff);
    k_place<<<NB_SCAN, 256, 0, stream>>>(cntp, goff, perm);

    auto slot = [&](int k) { return pool + (size_t)((k - 1) & (SLOTS - 1)) * CHAIN_ELEMS; };
    const int GRID_C = (int)(CH4 / 256);   // 3125

    auto launch_combine = [&](int nt, const float* src, float* accb,
                              CombCfg& cfg, int first, int doabs) {
        const float4* s4 = (const float4*)src;
        const float4* p4 = (const float4*)pool;
        float4* a4 = (float4*)accb;
        if (CAD == 8) {
            if (nt == 4) k_combine<8, 4><<<GRID_C, 256, 0, stream>>>(s4, p4, a4, cfg, first, doabs);
            if (nt == 3) k_combine<8, 3><<<GRID_C, 256, 0, stream>>>(s4, p4, a4, cfg, first, doabs);
            if (nt == 2) k_combine<8, 2><<<GRID_C, 256, 0, stream>>>(s4, p4, a4, cfg, first, doabs);
            if (nt == 1) k_combine<8, 1><<<GRID_C, 256, 0, stream>>>(s4, p4, a4, cfg, first, doabs);
        } else {
            if (nt == 4) k_combine<4, 4><<<GRID_C, 256, 0, stream>>>(s4, p4, a4, cfg, first, doabs);
            if (nt == 3) k_combine<4, 3><<<GRID_C, 256, 0, stream>>>(s4, p4, a4, cfg, first, doabs);
            if (nt == 2) k_combine<4, 2><<<GRID_C, 256, 0, stream>>>(s4, p4, a4, cfg, first, doabs);
            if (nt == 1) k_combine<4, 1><<<GRID_C, 256, 0, stream>>>(s4, p4, a4, cfg, first, doabs);
        }
    };

    // run one chain: src [NN,64] -> acc planes of accb
    auto run_chain = [&](const float* src, float* accb,
                         const int* scl, const int* pln, int nt) {
        k_prop<true><<<GRID_PROP, 256, 0, stream>>>(src, nullptr, slot(1),
                                                    offp, cntp, csrp, perm);
        for (int k = 2; k <= 16; ++k) {
            const float* Tprev = (k == 2) ? src : slot(k - 2);
            k_prop<false><<<GRID_PROP, 256, 0, stream>>>(slot(k - 1), Tprev, slot(k),
                                                         offp, cntp, csrp, perm);
            if ((k % CAD) == 0) {
                CombCfg cfg;
                for (int t = 0; t < nt; ++t) {
                    int si = scl[t];
                    cfg.c0[t] = 0.5f * C[0][si];
                    cfg.plane[t] = pln[t];
                    for (int m = 0; m < CAD; ++m) cfg.ck[t][m] = C[k - CAD + 1 + m][si];
                }
                launch_combine(nt, src, accb, cfg, (k == CAD) ? 1 : 0,
                               (k == 16) ? 1 : 0);
            }
        }
    };

    // ---- phase 1: x -> hacc planes 0..3 (|h| per scale) ----
    {
        const int scl[4] = {0, 1, 2, 3};
        const int pln[4] = {0, 1, 2, 3};
        run_chain(x, hacc, scl, pln, 4);
    }

    // ---- phase 2: 3 chains on hacc planes 0..2 ----
    {
        const int scl0[3] = {1, 2, 3}; const int pln0[3] = {0, 1, 3};
        run_chain(hacc + 0 * CHAIN_ELEMS, acc2, scl0, pln0, 3);
        const int scl1[2] = {2, 3};    const int pln1[2] = {2, 4};
        run_chain(hacc + 1 * CHAIN_ELEMS, acc2, scl1, pln1, 2);
        const int scl2[1] = {3};       const int pln2[1] = {5};
        run_chain(hacc + 2 * CHAIN_ELEMS, acc2, scl2, pln2, 1);
    }

    // ---- moments ----
    dim3 mg(3, NGRAPH);
    k_moments<<<mg, 256, 0, stream>>>(x, hacc, acc2, out);
}

// Round 13
// 2295.138 us; speedup vs baseline: 1.4035x; 1.0694x over previous
//
#include <hip/hip_runtime.h>
#include <math.h>

#define NN 50000
#define NE 800000
#define NGRAPH 100
#define NPG 500
#define NB_SCAN 196
#define CHAIN_ELEMS ((size_t)NN * 64)
#define CH4 ((size_t)NN * 16)          // float4 elements per plane
#define GRID_PROP (NN / 4)             // 4 nodes (waves) per 256-thr block

typedef long long ll;

__device__ __forceinline__ void unpack(ll v, int& r, float& w) {
    r = (int)(v & 0xffffffffLL);
    w = __int_as_float((int)(v >> 32));
}

__device__ __forceinline__ float4 f4fma(float w, float4 v, float4 a) {
    a.x += w * v.x; a.y += w * v.y; a.z += w * v.z; a.w += w * v.w;
    return a;
}

// ---------------- setup kernels ----------------

__global__ void k_deg(const int* __restrict__ col, int* __restrict__ degi) {
    int e = blockIdx.x * blockDim.x + threadIdx.x;
    if (e < NE) atomicAdd(&degi[col[e]], 1);
}

__global__ void k_dh(const int* __restrict__ degi, float* __restrict__ dh) {
    int i = blockIdx.x * blockDim.x + threadIdx.x;
    if (i < NN) {
        int d = degi[i];
        dh[i] = d > 0 ? (float)(1.0 / sqrt((double)d)) : 0.0f;
    }
}

__global__ void k_bsum(const int* __restrict__ cnt, int* __restrict__ bsum) {
    __shared__ int sh[256];
    int i = blockIdx.x * 256 + threadIdx.x;
    sh[threadIdx.x] = (i < NN) ? cnt[i] : 0;
    __syncthreads();
    for (int s = 128; s > 0; s >>= 1) {
        if (threadIdx.x < s) sh[threadIdx.x] += sh[threadIdx.x + s];
        __syncthreads();
    }
    if (threadIdx.x == 0) bsum[blockIdx.x] = sh[0];
}

__global__ void k_bscan(const int* __restrict__ bsum, int* __restrict__ boff) {
    __shared__ int sh[2][256];
    int v = (threadIdx.x < NB_SCAN) ? bsum[threadIdx.x] : 0;
    int cur = 0;
    sh[0][threadIdx.x] = v;
    __syncthreads();
    for (int s = 1; s < 256; s <<= 1) {
        int val = sh[cur][threadIdx.x];
        if ((int)threadIdx.x >= s) val += sh[cur][threadIdx.x - s];
        sh[cur ^ 1][threadIdx.x] = val;
        cur ^= 1;
        __syncthreads();
    }
    if (threadIdx.x < NB_SCAN) boff[threadIdx.x] = sh[cur][threadIdx.x] - v;
}

__global__ void k_scan2(const int* __restrict__ cnt, const int* __restrict__ boff,
                        int* __restrict__ off) {
    __shared__ int sh[2][256];
    int i = blockIdx.x * 256 + threadIdx.x;
    int v = (i < NN) ? cnt[i] : 0;
    int cur = 0;
    sh[0][threadIdx.x] = v;
    __syncthreads();
    for (int s = 1; s < 256; s <<= 1) {
        int val = sh[cur][threadIdx.x];
        if ((int)threadIdx.x >= s) val += sh[cur][threadIdx.x - s];
        sh[cur ^ 1][threadIdx.x] = val;
        cur ^= 1;
        __syncthreads();
    }
    if (i < NN) off[i] = boff[blockIdx.x] + sh[cur][threadIdx.x] - v;
}

__global__ void k_fill(const int* __restrict__ row, const int* __restrict__ col,
                       const float* __restrict__ dh, const int* __restrict__ off,
                       int* __restrict__ cursor, ll* __restrict__ csrp) {
    int e = blockIdx.x * blockDim.x + threadIdx.x;
    if (e >= NE) return;
    int r = row[e], c = col[e];
    int pos = off[c] + atomicAdd(&cursor[c], 1);
    float w = dh[r] * dh[c];
    csrp[pos] = ((ll)__float_as_int(w) << 32) | (unsigned int)r;
}

// ---------------- recurrence kernel (fp32, [NN][64], float4 gathers) --------
// wave = 1 node. lane = eg*16 + cq: eg = edge subgroup (0..3), cq = col quad.
// Validated optimum (r9): 256 B row gathers, 2 accumulators, no indirection.

template <bool INIT>
__global__ __launch_bounds__(256) void k_prop(
    const float* __restrict__ Tcur, const float* __restrict__ Tprev,
    float* __restrict__ Tnext, const int* __restrict__ off,
    const int* __restrict__ degi, const ll* __restrict__ csrp) {
    int node = blockIdx.x * 4 + (threadIdx.x >> 6);
    int lane = threadIdx.x & 63;
    int eg = lane >> 4;
    int cq = lane & 15;
    int s = off[node], e = s + degi[node];
    const float* tb = Tcur + (size_t)cq * 4;
    float4 a0 = make_float4(0.f, 0.f, 0.f, 0.f);
    float4 a1 = make_float4(0.f, 0.f, 0.f, 0.f);
    float4 pv = INIT ? make_float4(0.f, 0.f, 0.f, 0.f)
                     : *(const float4*)&Tprev[(size_t)node * 64 + cq * 4];
    int i = s;
    for (; i + 8 <= e; i += 8) {
        int r0, r1; float w0, w1;
        unpack(csrp[i + eg], r0, w0);
        unpack(csrp[i + 4 + eg], r1, w1);
        float4 v0 = *(const float4*)(tb + (size_t)r0 * 64);
        float4 v1 = *(const float4*)(tb + (size_t)r1 * 64);
        a0 = f4fma(w0, v0, a0);
        a1 = f4fma(w1, v1, a1);
    }
    for (; i < e; i += 4) {
        int idx = i + eg;
        bool act = idx < e;
        int r; float w;
        unpack(csrp[act ? idx : (e - 1)], r, w);
        if (!act) w = 0.f;
        float4 v = *(const float4*)(tb + (size_t)r * 64);
        a0 = f4fma(w, v, a0);
    }
    float4 g = make_float4(a0.x + a1.x, a0.y + a1.y, a0.z + a1.z, a0.w + a1.w);
    g.x += __shfl_xor(g.x, 16); g.y += __shfl_xor(g.y, 16);
    g.z += __shfl_xor(g.z, 16); g.w += __shfl_xor(g.w, 16);
    g.x += __shfl_xor(g.x, 32); g.y += __shfl_xor(g.y, 32);
    g.z += __shfl_xor(g.z, 32); g.w += __shfl_xor(g.w, 32);
    float4 t;
    if (INIT) {
        t = make_float4(-g.x, -g.y, -g.z, -g.w);
    } else {
        t = make_float4(-2.f * g.x - pv.x, -2.f * g.y - pv.y,
                        -2.f * g.z - pv.z, -2.f * g.w - pv.w);
    }
    if (eg == 0) *(float4*)&Tnext[(size_t)node * 64 + cq * 4] = t;
}

// ---------------- combine: acc planes from NS pool slots (float4) -----------
// NS compile-time so tv[] stays in VGPRs (r7's runtime ns spilled to scratch).

struct CombCfg {
    float c0[4];
    float ck[4][8];
    int   plane[4];
};

template <int NS, int NT>
__global__ __launch_bounds__(256) void k_combine(
    const float4* __restrict__ src0, const float4* __restrict__ pool,
    float4* __restrict__ accb, CombCfg cfg, int first, int doabs) {
    size_t v = (size_t)blockIdx.x * 256 + threadIdx.x;   // < NN*16
    float4 tv[NS];
#pragma unroll
    for (int m = 0; m < NS; ++m) tv[m] = pool[(size_t)m * CH4 + v];
    float4 s0 = first ? src0[v] : make_float4(0.f, 0.f, 0.f, 0.f);
#pragma unroll
    for (int t = 0; t < NT; ++t) {
        size_t o = (size_t)cfg.plane[t] * CH4 + v;
        float4 a;
        if (first) {
            float c = cfg.c0[t];
            a = make_float4(c * s0.x, c * s0.y, c * s0.z, c * s0.w);
        } else {
            a = accb[o];
        }
#pragma unroll
        for (int m = 0; m < NS; ++m) a = f4fma(cfg.ck[t][m], tv[m], a);
        if (doabs) a = make_float4(fabsf(a.x), fabsf(a.y), fabsf(a.z), fabsf(a.w));
        accb[o] = a;
    }
}

// ---------------- moments ----------------
__global__ void k_moments(const float* __restrict__ x, const float* __restrict__ hacc,
                          const float* __restrict__ acc2, float* __restrict__ out) {
    int g = blockIdx.y;
    int col = blockIdx.x * 256 + threadIdx.x;
    if (col >= 704) return;
    const float* src;
    int c0;
    if (col < 64)       { src = x;    c0 = col; }
    else if (col < 320) { int p = (col - 64) >> 6;  src = hacc + (size_t)p * CHAIN_ELEMS; c0 = (col - 64) & 63; }
    else                { int p = (col - 320) >> 6; src = acc2 + (size_t)p * CHAIN_ELEMS; c0 = (col - 320) & 63; }
    double s1 = 0, s2 = 0, s3 = 0, s4 = 0;
    int base = g * NPG;
    for (int i = 0; i < NPG; ++i) {
        double v = (double)src[(size_t)(base + i) * 64 + c0];
        double v2 = v * v;
        s1 += v; s2 += v2; s3 += v2 * v; s4 += v2 * v2;
    }
    double n = (double)NPG;
    double mu = s1 / n;
    double E2 = s2 / n, E3 = s3 / n, E4 = s4 / n;
    double m2 = E2 - mu * mu;
    double m3 = E3 - 3.0 * mu * E2 + 2.0 * mu * mu * mu;
    double m4 = E4 - 4.0 * mu * E3 + 6.0 * mu * mu * E2 - 3.0 * mu * mu * mu * mu;
    float m2f = (float)m2;
    float skew = 0.f, kurt = -3.f;
    if (m2f > 0.f) {
        skew = (float)(m3 / (m2 * sqrt(m2)));
        if (skew > 1e15f) skew = 0.f;
        kurt = (float)(m4 / (m2 * m2) - 3.0);
        if (kurt > 1e15f) kurt = -3.f;
    }
    size_t ob = (size_t)g * 2816 + col;
    out[ob]        = (float)mu;
    out[ob + 704]  = m2f;
    out[ob + 1408] = skew;
    out[ob + 2112] = kurt;
}

// ---------------- host ----------------

extern "C" void kernel_launch(void* const* d_in, const int* in_sizes, int n_in,
                              void* d_out, int out_size, void* d_ws, size_t ws_size,
                              hipStream_t stream) {
    const float* x = (const float*)d_in[0];
    const int* ei  = (const int*)d_in[1];
    const int* row = ei;
    const int* col = ei + NE;
    float* out = (float*)d_out;

    // Chebyshev coefficients [17][4], double precision (matches numpy)
    float C[17][4];
    {
        const int Nc = 17;
        const int scales[4] = {2, 4, 8, 16};
        for (int si = 0; si < 4; ++si) {
            double ker[17];
            for (int j = 0; j < Nc; ++j) {
                double num = cos(M_PI * (j + 0.5) / Nc);
                double b = -num;
                double v = pow(b, (double)(scales[si] / 2)) - pow(b, (double)scales[si]);
                if (v < 0) v = 0;
                ker[j] = sqrt(v);
            }
            for (int o = 0; o < Nc; ++o) {
                double acc = 0;
                for (int j = 0; j < Nc; ++j) acc += ker[j] * cos(M_PI * o * (j + 0.5) / Nc);
                C[o][si] = (float)(2.0 / Nc * acc);
            }
        }
    }

    // workspace carve: 8-slot pool (~238 MB, fits in 256 MB L3); fallback 4 (~186)
    int*   degi; float* dh; int* off; int* cursor; int* bsum; int* boff;
    ll*    csrp; float* pool; float* hacc; float* acc2;
    int SLOTS = 8;
    for (int attempt = 0; attempt < 2; ++attempt) {
        char* p = (char*)d_ws;
        auto alloc = [&](size_t bytes) -> void* {
            void* r = (void*)p;
            p += (bytes + 255) & ~(size_t)255;
            return r;
        };
        degi   = (int*)alloc((size_t)NN * 4);
        dh     = (float*)alloc((size_t)NN * 4);
        off    = (int*)alloc((size_t)NN * 4);
        cursor = (int*)alloc((size_t)NN * 4);
        bsum   = (int*)alloc((size_t)NB_SCAN * 4);
        boff   = (int*)alloc((size_t)NB_SCAN * 4);
        csrp   = (ll*)alloc((size_t)NE * 8);
        pool   = (float*)alloc((size_t)SLOTS * CHAIN_ELEMS * 4);
        hacc   = (float*)alloc((size_t)4 * CHAIN_ELEMS * 4);
        acc2   = (float*)alloc((size_t)6 * CHAIN_ELEMS * 4);
        if ((size_t)(p - (char*)d_ws) <= ws_size) break;
        SLOTS = 4;
    }
    const int CAD = SLOTS;   // combine cadence

    hipMemsetAsync(degi, 0, (size_t)NN * 4, stream);
    hipMemsetAsync(cursor, 0, (size_t)NN * 4, stream);

    k_deg  <<<(NE + 255) / 256, 256, 0, stream>>>(col, degi);
    k_dh   <<<(NN + 255) / 256, 256, 0, stream>>>(degi, dh);
    k_bsum <<<NB_SCAN, 256, 0, stream>>>(degi, bsum);
    k_bscan<<<1, 256, 0, stream>>>(bsum, boff);
    k_scan2<<<NB_SCAN, 256, 0, stream>>>(degi, boff, off);
    k_fill <<<(NE + 255) / 256, 256, 0, stream>>>(row, col, dh, off, cursor, csrp);

    auto slot = [&](int k) { return pool + (size_t)((k - 1) & (SLOTS - 1)) * CHAIN_ELEMS; };
    const int GRID_C = (int)(CH4 / 256);   // 3125

    auto launch_combine = [&](int nt, const float* src, float* accb,
                              CombCfg& cfg, int first, int doabs) {
        const float4* s4 = (const float4*)src;
        const float4* p4 = (const float4*)pool;
        float4* a4 = (float4*)accb;
        if (CAD == 8) {
            if (nt == 4) k_combine<8, 4><<<GRID_C, 256, 0, stream>>>(s4, p4, a4, cfg, first, doabs);
            if (nt == 3) k_combine<8, 3><<<GRID_C, 256, 0, stream>>>(s4, p4, a4, cfg, first, doabs);
            if (nt == 2) k_combine<8, 2><<<GRID_C, 256, 0, stream>>>(s4, p4, a4, cfg, first, doabs);
            if (nt == 1) k_combine<8, 1><<<GRID_C, 256, 0, stream>>>(s4, p4, a4, cfg, first, doabs);
        } else {
            if (nt == 4) k_combine<4, 4><<<GRID_C, 256, 0, stream>>>(s4, p4, a4, cfg, first, doabs);
            if (nt == 3) k_combine<4, 3><<<GRID_C, 256, 0, stream>>>(s4, p4, a4, cfg, first, doabs);
            if (nt == 2) k_combine<4, 2><<<GRID_C, 256, 0, stream>>>(s4, p4, a4, cfg, first, doabs);
            if (nt == 1) k_combine<4, 1><<<GRID_C, 256, 0, stream>>>(s4, p4, a4, cfg, first, doabs);
        }
    };

    // run one chain: src [NN,64] -> acc planes of accb
    auto run_chain = [&](const float* src, float* accb,
                         const int* scl, const int* pln, int nt) {
        k_prop<true><<<GRID_PROP, 256, 0, stream>>>(src, nullptr, slot(1),
                                                    off, degi, csrp);
        for (int k = 2; k <= 16; ++k) {
            const float* Tprev = (k == 2) ? src : slot(k - 2);
            k_prop<false><<<GRID_PROP, 256, 0, stream>>>(slot(k - 1), Tprev, slot(k),
                                                         off, degi, csrp);
            if ((k % CAD) == 0) {
                CombCfg cfg;
                for (int t = 0; t < nt; ++t) {
                    int si = scl[t];
                    cfg.c0[t] = 0.5f * C[0][si];
                    cfg.plane[t] = pln[t];
                    for (int m = 0; m < CAD; ++m) cfg.ck[t][m] = C[k - CAD + 1 + m][si];
                }
                launch_combine(nt, src, accb, cfg, (k == CAD) ? 1 : 0,
                               (k == 16) ? 1 : 0);
            }
        }
    };

    // ---- phase 1: x -> hacc planes 0..3 (|h| per scale) ----
    {
        const int scl[4] = {0, 1, 2, 3};
        const int pln[4] = {0, 1, 2, 3};
        run_chain(x, hacc, scl, pln, 4);
    }

    // ---- phase 2: 3 chains on hacc planes 0..2 ----
    {
        const int scl0[3] = {1, 2, 3}; const int pln0[3] = {0, 1, 3};
        run_chain(hacc + 0 * CHAIN_ELEMS, acc2, scl0, pln0, 3);
        const int scl1[2] = {2, 3};    const int pln1[2] = {2, 4};
        run_chain(hacc + 1 * CHAIN_ELEMS, acc2, scl1, pln1, 2);
        const int scl2[1] = {3};       const int pln2[1] = {5};
        run_chain(hacc + 2 * CHAIN_ELEMS, acc2, scl2, pln2, 1);
    }

    // ---- moments ----
    dim3 mg(3, NGRAPH);
    k_moments<<<mg, 256, 0, stream>>>(x, hacc, acc2, out);
}